// Round 1
// baseline (6436.980 us; speedup 1.0000x reference)
//
#include <hip/hip_runtime.h>
#include <hip/hip_bf16.h>
#include <cstddef>

// Problem constants
#define B_  512
#define L_  200
#define D_  256
#define K_  2048
#define BL_ (B_ * L_)

// ---------------------------------------------------------------------------
// K1: cnorm[k] = sum_d code_book[k][d]^2   (one wave per code)
// ---------------------------------------------------------------------------
__global__ __launch_bounds__(256) void cnorm_kernel(const float* __restrict__ cb,
                                                    float* __restrict__ cnorm) {
    int wave = (blockIdx.x * blockDim.x + threadIdx.x) >> 6;  // code id
    int lane = threadIdx.x & 63;
    if (wave >= K_) return;
    const float* row = cb + (size_t)wave * D_;
    float s = 0.f;
    #pragma unroll
    for (int i = 0; i < D_ / 64; ++i) {
        float v = row[lane + 64 * i];
        s = fmaf(v, v, s);
    }
    #pragma unroll
    for (int off = 32; off; off >>= 1) s += __shfl_down(s, off);
    if (lane == 0) cnorm[wave] = s;
}

// ---------------------------------------------------------------------------
// K2: per-position argmin_k ( cnorm[k] - 2 * e . c_k )
//   block = 256 threads, MP=32 positions/block, 8 code-slices,
//   KB=16 codes register-blocked per thread (LDS traffic = FLOPs/16).
// ---------------------------------------------------------------------------
#define MP 32
#define KB 16
#define LDSTRIDE 260   // 260 % 32 == 4 -> only 4-way conflict on b128; 16B aligned rows

__global__ __launch_bounds__(256) void argmin_kernel(
    const int* __restrict__ ids, const int* __restrict__ masks,
    const float* __restrict__ table, const float* __restrict__ cb,
    const float* __restrict__ cnorm, int* __restrict__ out_idx) {

    __shared__ float se[MP][LDSTRIDE];
    __shared__ float sbest[8][MP];
    __shared__ int   sbidx[8][MP];

    const int t  = threadIdx.x;
    const int u0 = blockIdx.x * MP;

    // ---- load phase: gather 32 embedding rows, apply mask, stage in LDS ----
    {
        int p  = t >> 3;       // 0..31 position in tile
        int f0 = t & 7;        // float4 slot
        int u  = u0 + p;
        int id = ids[u];
        float m = (masks[u] >= 1) ? 1.0f : 0.0f;
        const float4* row = (const float4*)(table + (size_t)id * D_);
        #pragma unroll
        for (int i = 0; i < 8; ++i) {
            int f = f0 + 8 * i;
            float4 v = row[f];
            v.x *= m; v.y *= m; v.z *= m; v.w *= m;
            *(float4*)&se[p][4 * f] = v;
        }
    }
    __syncthreads();

    // ---- compute phase ----
    const int p = t & 31;
    const int s = t >> 5;      // code slice 0..7
    float best = 3.4e38f;
    int   bidx = 0;

    for (int g = 0; g < K_ / (8 * KB); ++g) {          // 16 groups
        const int kbase = g * (8 * KB) + s * KB;
        const float* cbase = cb + (size_t)kbase * D_;
        float acc[KB];
        #pragma unroll
        for (int j = 0; j < KB; ++j) acc[j] = 0.f;

        for (int d = 0; d < D_; d += 4) {
            float4 e = *(const float4*)&se[p][d];
            #pragma unroll
            for (int j = 0; j < KB; ++j) {
                float4 c = *(const float4*)&cbase[j * D_ + d];
                acc[j] = fmaf(e.x, c.x, fmaf(e.y, c.y, fmaf(e.z, c.z, fmaf(e.w, c.w, acc[j]))));
            }
        }
        #pragma unroll
        for (int j = 0; j < KB; ++j) {
            float sc = cnorm[kbase + j] - 2.0f * acc[j];
            if (sc < best) { best = sc; bidx = kbase + j; }  // increasing k + strict '<' = first-min
        }
    }

    sbest[s][p] = best;
    sbidx[s][p] = bidx;
    __syncthreads();

    if (t < MP) {
        float b0 = sbest[0][t]; int i0 = sbidx[0][t];
        #pragma unroll
        for (int ss = 1; ss < 8; ++ss) {
            float bs = sbest[ss][t]; int is = sbidx[ss][t];
            if (bs < b0 || (bs == b0 && is < i0)) { b0 = bs; i0 = is; }
        }
        out_idx[u0 + t] = i0;
    }
}

// ---------------------------------------------------------------------------
// K3: per-batch reduction + concat + dense.
//   block b: thread d accumulates emb_sum[d], vq_sum[d] over L;
//   x = [vq_sum/cnt, emb_sum/(cnt+1e-9)]; out = x @ W + b.
// ---------------------------------------------------------------------------
__global__ __launch_bounds__(256) void reduce_dense_kernel(
    const int* __restrict__ ids, const int* __restrict__ masks,
    const float* __restrict__ table, const float* __restrict__ cb,
    const int* __restrict__ vq_idx, const float* __restrict__ W,
    const float* __restrict__ bvec, float* __restrict__ out) {

    __shared__ float x[2 * D_];
    const int b = blockIdx.x;
    const int d = threadIdx.x;   // 0..255

    const int* idrow = ids    + b * L_;
    const int* mrow  = masks  + b * L_;
    const int* qrow  = vq_idx + b * L_;

    float esum = 0.f, vsum = 0.f;
    int count = 0;
    for (int l = 0; l < L_; ++l) {
        int id = idrow[l];
        int mv = mrow[l];
        int q  = qrow[l];
        float m = (mv >= 1) ? 1.0f : 0.0f;
        count += (mv >= 1) ? 1 : 0;
        esum = fmaf(m, table[(size_t)id * D_ + d], esum);
        vsum += cb[(size_t)q * D_ + d];           // includes masked positions (ref semantics)
    }
    float fc = (float)count;
    x[d]      = vsum / fc;            // vq_mean: no eps (matches tf vqvae)
    x[D_ + d] = esum / (fc + 1e-9f);  // hist_mean: +1e-9
    __syncthreads();

    float acc = bvec[d];
    for (int i = 0; i < 2 * D_; ++i)
        acc = fmaf(x[i], W[i * D_ + d], acc);
    out[(size_t)b * D_ + d] = acc;
}

// ---------------------------------------------------------------------------
extern "C" void kernel_launch(void* const* d_in, const int* in_sizes, int n_in,
                              void* d_out, int out_size, void* d_ws, size_t ws_size,
                              hipStream_t stream) {
    const int*   ids   = (const int*)  d_in[0];   // [B,L] int32
    const int*   masks = (const int*)  d_in[1];   // [B,L] int32
    const float* table = (const float*)d_in[2];   // [V,D]
    const float* cb    = (const float*)d_in[3];   // [K,D]
    const float* W     = (const float*)d_in[4];   // [2D,D]
    const float* bvec  = (const float*)d_in[5];   // [D]
    float* out = (float*)d_out;

    float* cnorm = (float*)d_ws;                       // 2048 floats
    int*   idx   = (int*)((char*)d_ws + K_ * sizeof(float));  // 102400 ints

    // K1: codebook norms (2048 waves)
    cnorm_kernel<<<(K_ * 64) / 256, 256, 0, stream>>>(cb, cnorm);

    // K2: argmin per position
    argmin_kernel<<<BL_ / MP, 256, 0, stream>>>(ids, masks, table, cb, cnorm, idx);

    // K3: reductions + dense
    reduce_dense_kernel<<<B_, 256, 0, stream>>>(ids, masks, table, cb, idx, W, bvec, out);
}

// Round 2
// 470.366 us; speedup vs baseline: 13.6851x; 13.6851x over previous
//
#include <hip/hip_runtime.h>
#include <hip/hip_bf16.h>
#include <cstddef>
#include <cstdint>

#define B_  512
#define L_  200
#define D_  256
#define K_  2048
#define BL_ (B_ * L_)

typedef __bf16 bf16x8 __attribute__((ext_vector_type(8)));
typedef float  f32x16 __attribute__((ext_vector_type(16)));

#define GL_LDS(g, l) __builtin_amdgcn_global_load_lds(                          \
    (const __attribute__((address_space(1))) void*)(g),                         \
    (__attribute__((address_space(3))) void*)(l), 16, 0, 0)

__device__ inline ushort f2bf(float f) {   // RNE float->bf16 (no NaN in data)
    union { float f; uint u; } a; a.f = f;
    uint r = a.u + 0x7FFFu + ((a.u >> 16) & 1u);
    return (ushort)(r >> 16);
}

// ---------------------------------------------------------------------------
// prep: cnorm[k] = ||c_k||^2 (fp32) and bf16 codebook copy. One wave per code.
// ---------------------------------------------------------------------------
__global__ __launch_bounds__(256) void prep_kernel(const float* __restrict__ cb,
                                                   float* __restrict__ cnorm,
                                                   ushort* __restrict__ cbbf) {
    int code = (blockIdx.x * 256 + threadIdx.x) >> 6;
    int lane = threadIdx.x & 63;
    float4 v = ((const float4*)(cb + (size_t)code * D_))[lane];
    float s = v.x * v.x + v.y * v.y + v.z * v.z + v.w * v.w;
    #pragma unroll
    for (int off = 32; off; off >>= 1) s += __shfl_down(s, off);
    union { ushort us[4]; uint2 u2; } pk;
    pk.us[0] = f2bf(v.x); pk.us[1] = f2bf(v.y); pk.us[2] = f2bf(v.z); pk.us[3] = f2bf(v.w);
    ((uint2*)(cbbf + (size_t)code * D_))[lane] = pk.u2;
    if (lane == 0) cnorm[code] = s;
}

// ---------------------------------------------------------------------------
// gemm_top2: per 128-row block compute scores = cnorm[k] - 2*E.C^T over all
// K=2048 codes via bf16 MFMA; keep per-row top-2 candidates.
//   4 waves: wave = (rowhalf, colhalf); wave tile = 64 rows x 32 cols/chunk.
//   A (embeddings) gathered+masked into registers once (2x16 bf16x8 frags).
//   C chunk (64 codes x 512B) staged in LDS, XOR-swizzled 16B units.
//   Selection scan of chunk nc-1 fused into chunk nc's K-loop.
// ---------------------------------------------------------------------------
__global__ __launch_bounds__(256, 2) void gemm_top2_kernel(
    const int* __restrict__ ids, const int* __restrict__ masks,
    const float* __restrict__ table, const ushort* __restrict__ cbbf,
    const float* __restrict__ cnorm, int2* __restrict__ cand) {

    __shared__ ushort cbuf[64 * 256];     // 32 KB
    __shared__ float  scorebuf[64 * 128]; // 32 KB: [col][(row+col)&127]

    const int t = threadIdx.x;
    const int lane = t & 63;
    const int l31 = lane & 31;
    const int h = lane >> 5;
    const int w = t >> 6;
    const int rowhalf = w >> 1;
    const int colhalf = w & 1;
    const int blk = blockIdx.x;

    // ---- A fragments: 64 rows x K=256, bf16, in registers ----
    bf16x8 afrag[2][16];
    #pragma unroll
    for (int mt = 0; mt < 2; ++mt) {
        int r = blk * 128 + rowhalf * 64 + mt * 32 + l31;
        int id = ids[r];
        float m = (masks[r] >= 1) ? 1.0f : 0.0f;
        const float* er = table + (size_t)id * D_ + h * 8;
        #pragma unroll
        for (int ks = 0; ks < 16; ++ks) {
            float4 x = *(const float4*)(er + ks * 16);
            float4 y = *(const float4*)(er + ks * 16 + 4);
            bf16x8 a;
            a[0] = (__bf16)(x.x * m); a[1] = (__bf16)(x.y * m);
            a[2] = (__bf16)(x.z * m); a[3] = (__bf16)(x.w * m);
            a[4] = (__bf16)(y.x * m); a[5] = (__bf16)(y.y * m);
            a[6] = (__bf16)(y.z * m); a[7] = (__bf16)(y.w * m);
            afrag[mt][ks] = a;
        }
    }

    // init scorebuf to +inf (chunk -1 scan reads it harmlessly)
    #pragma unroll
    for (int i = 0; i < 32; ++i) scorebuf[i * 256 + t] = 3.0e38f;

    // stage chunk 0: 64 codes x 32 units of 16B, unit u' holds global unit u'^(n&7)
    {
        int base = __builtin_amdgcn_readfirstlane((t >> 6) * 1024);
        #pragma unroll
        for (int i = 0; i < 8; ++i) {
            int slot = i * 256 + t;
            int n = slot >> 5, up = slot & 31;
            int u = up ^ (n & 7);
            GL_LDS(cbbf + ((size_t)n << 8) + (u << 3), (char*)cbuf + i * 4096 + base);
        }
    }
    __syncthreads();

    const int nloc = colhalf * 32 + l31;
    const int nswz = nloc & 7;
    const char* cbB = (const char*)cbuf + (size_t)nloc * 512;
    const int myrow = t & 127;
    const int scanc0 = (t >> 7) * 32;

    float b1 = 3.0e38f, b2 = 3.0e38f;
    int i1 = 0, i2 = 0;

    for (int nc = 0; nc < 32; ++nc) {
        f32x16 acc0, acc1;
        #pragma unroll
        for (int j = 0; j < 16; ++j) { acc0[j] = 0.f; acc1[j] = 0.f; }

        const int colgprev = (nc - 1) * 64 + scanc0;

        #pragma unroll
        for (int ks = 0; ks < 16; ++ks) {
            bf16x8 bf = *(const bf16x8*)(cbB + (((2 * ks + h) ^ nswz) << 4));
            acc0 = __builtin_amdgcn_mfma_f32_32x32x16_bf16(afrag[0][ks], bf, acc0, 0, 0, 0);
            acc1 = __builtin_amdgcn_mfma_f32_32x32x16_bf16(afrag[1][ks], bf, acc1, 0, 0, 0);
            // fused top-2 scan of previous chunk (2 elems per ks, hides under MFMA)
            #pragma unroll
            for (int e = 0; e < 2; ++e) {
                int cc = 2 * ks + e;
                int c = scanc0 + cc;
                float s = scorebuf[c * 128 + ((myrow + c) & 127)];
                int colg = colgprev + cc;
                bool c1v = s < b1, c2v = s < b2;
                b2 = c1v ? b1 : (c2v ? s : b2);
                i2 = c1v ? i1 : (c2v ? colg : i2);
                b1 = c1v ? s : b1;
                i1 = c1v ? colg : i1;
            }
        }
        __syncthreads();   // all waves done reading cbuf + scorebuf

        // stage next chunk (async; drains at next barrier)
        if (nc < 31) {
            int n0 = (nc + 1) * 64;
            int base = __builtin_amdgcn_readfirstlane((t >> 6) * 1024);
            #pragma unroll
            for (int i = 0; i < 8; ++i) {
                int slot = i * 256 + t;
                int n = slot >> 5, up = slot & 31;
                int u = up ^ (n & 7);
                GL_LDS(cbbf + ((size_t)(n0 + n) << 8) + (u << 3),
                       (char*)cbuf + i * 4096 + base);
            }
        }

        // score write: scores[c][(row+c)&127] = cnorm - 2*dot
        {
            int colg = nc * 64 + nloc;
            float cn = cnorm[colg];
            #pragma unroll
            for (int mt = 0; mt < 2; ++mt) {
                #pragma unroll
                for (int j = 0; j < 16; ++j) {
                    float a = mt ? acc1[j] : acc0[j];
                    int row = rowhalf * 64 + mt * 32 + (j & 3) + 8 * (j >> 2) + 4 * h;
                    scorebuf[nloc * 128 + ((row + nloc) & 127)] = cn - 2.0f * a;
                }
            }
        }
        __syncthreads();
    }

    // standalone scan of last chunk
    {
        const int colgprev = 31 * 64 + scanc0;
        #pragma unroll
        for (int cc = 0; cc < 32; ++cc) {
            int c = scanc0 + cc;
            float s = scorebuf[c * 128 + ((myrow + c) & 127)];
            int colg = colgprev + cc;
            bool c1v = s < b1, c2v = s < b2;
            b2 = c1v ? b1 : (c2v ? s : b2);
            i2 = c1v ? i1 : (c2v ? colg : i2);
            b1 = c1v ? s : b1;
            i1 = c1v ? colg : i1;
        }
    }
    __syncthreads();

    // merge the two col-halves per row (reuse cbuf as scratch)
    float* mb = (float*)cbuf;
    int*   ib = (int*)cbuf + 256;
    if (t >> 7) { mb[myrow] = b1; mb[128 + myrow] = b2; ib[myrow] = i1; ib[128 + myrow] = i2; }
    __syncthreads();
    if (!(t >> 7)) {
        float Bb1 = mb[myrow], Bb2 = mb[128 + myrow];
        int   Bi1 = ib[myrow], Bi2 = ib[128 + myrow];
        int g1, g2;
        if (Bb1 < b1) { g1 = Bi1; g2 = (b1 < Bb2) ? i1 : Bi2; }
        else          { g1 = i1;  g2 = (Bb1 < b2) ? Bi1 : i2; }
        cand[blk * 128 + myrow] = make_int2(g1, g2);
    }
}

// ---------------------------------------------------------------------------
// rescore: exact fp32 distance for the 2 candidates; first-min tie-break.
// One wave per position.
// ---------------------------------------------------------------------------
__global__ __launch_bounds__(256) void rescore_kernel(
    const int* __restrict__ ids, const int* __restrict__ masks,
    const float* __restrict__ table, const float* __restrict__ cb,
    const float* __restrict__ cnorm, const int2* __restrict__ cand,
    int* __restrict__ idx_out) {

    int u = blockIdx.x * 4 + (threadIdx.x >> 6);
    int lane = threadIdx.x & 63;
    int2 c = cand[u];
    int lo = min(c.x, c.y), hi = max(c.x, c.y);
    int id = ids[u];
    float m = (masks[u] >= 1) ? 1.0f : 0.0f;
    float4 e = ((const float4*)(table + (size_t)id * D_))[lane];
    e.x *= m; e.y *= m; e.z *= m; e.w *= m;
    float4 a = ((const float4*)(cb + (size_t)lo * D_))[lane];
    float4 b = ((const float4*)(cb + (size_t)hi * D_))[lane];
    float s1 = fmaf(e.x, a.x, fmaf(e.y, a.y, fmaf(e.z, a.z, e.w * a.w)));
    float s2 = fmaf(e.x, b.x, fmaf(e.y, b.y, fmaf(e.z, b.z, e.w * b.w)));
    #pragma unroll
    for (int off = 32; off; off >>= 1) {
        s1 += __shfl_xor(s1, off);
        s2 += __shfl_xor(s2, off);
    }
    if (lane == 0) {
        float d1 = cnorm[lo] - 2.0f * s1;
        float d2 = cnorm[hi] - 2.0f * s2;
        idx_out[u] = (d2 < d1) ? hi : lo;   // tie -> lo (first minimum)
    }
}

// ---------------------------------------------------------------------------
// reduce_dense: per-batch masked means + concat + dense (unchanged).
// ---------------------------------------------------------------------------
__global__ __launch_bounds__(256) void reduce_dense_kernel(
    const int* __restrict__ ids, const int* __restrict__ masks,
    const float* __restrict__ table, const float* __restrict__ cb,
    const int* __restrict__ vq_idx, const float* __restrict__ W,
    const float* __restrict__ bvec, float* __restrict__ out) {

    __shared__ float x[2 * D_];
    const int b = blockIdx.x;
    const int d = threadIdx.x;

    const int* idrow = ids    + b * L_;
    const int* mrow  = masks  + b * L_;
    const int* qrow  = vq_idx + b * L_;

    float esum = 0.f, vsum = 0.f;
    int count = 0;
    for (int l = 0; l < L_; ++l) {
        int id = idrow[l];
        int mv = mrow[l];
        int q  = qrow[l];
        float m = (mv >= 1) ? 1.0f : 0.0f;
        count += (mv >= 1) ? 1 : 0;
        esum = fmaf(m, table[(size_t)id * D_ + d], esum);
        vsum += cb[(size_t)q * D_ + d];
    }
    float fc = (float)count;
    x[d]      = vsum / fc;
    x[D_ + d] = esum / (fc + 1e-9f);
    __syncthreads();

    float acc = bvec[d];
    for (int i = 0; i < 2 * D_; ++i)
        acc = fmaf(x[i], W[i * D_ + d], acc);
    out[(size_t)b * D_ + d] = acc;
}

// ---------------------------------------------------------------------------
extern "C" void kernel_launch(void* const* d_in, const int* in_sizes, int n_in,
                              void* d_out, int out_size, void* d_ws, size_t ws_size,
                              hipStream_t stream) {
    const int*   ids   = (const int*)  d_in[0];
    const int*   masks = (const int*)  d_in[1];
    const float* table = (const float*)d_in[2];
    const float* cb    = (const float*)d_in[3];
    const float* W     = (const float*)d_in[4];
    const float* bvec  = (const float*)d_in[5];
    float* out = (float*)d_out;

    float*  cnorm = (float*)d_ws;                                   // 8 KB
    ushort* cbbf  = (ushort*)((char*)d_ws + 8192);                  // 1 MB
    int2*   cand  = (int2*)((char*)d_ws + 8192 + 1048576);          // 800 KB
    int*    idx   = (int*)((char*)cand + (size_t)BL_ * sizeof(int2));

    prep_kernel<<<K_ * 64 / 256, 256, 0, stream>>>(cb, cnorm, cbbf);
    gemm_top2_kernel<<<BL_ / 128, 256, 0, stream>>>(ids, masks, table, cbbf, cnorm, cand);
    rescore_kernel<<<BL_ / 4, 256, 0, stream>>>(ids, masks, table, cb, cnorm, cand, idx);
    reduce_dense_kernel<<<B_, 256, 0, stream>>>(ids, masks, table, cb, idx, W, bvec, out);
}

// Round 3
// 414.886 us; speedup vs baseline: 15.5151x; 1.1337x over previous
//
#include <hip/hip_runtime.h>
#include <hip/hip_bf16.h>
#include <cstddef>
#include <cstdint>

#define B_  512
#define L_  200
#define D_  256
#define K_  2048
#define BL_ (B_ * L_)

typedef __bf16 bf16x8 __attribute__((ext_vector_type(8)));
typedef float  f32x16 __attribute__((ext_vector_type(16)));

#define GL_LDS(g, l) __builtin_amdgcn_global_load_lds(                          \
    (const __attribute__((address_space(1))) void*)(g),                         \
    (__attribute__((address_space(3))) void*)(l), 16, 0, 0)

__device__ inline ushort f2bf(float f) {   // RNE float->bf16 (no NaN in data)
    union { float f; uint u; } a; a.f = f;
    uint r = a.u + 0x7FFFu + ((a.u >> 16) & 1u);
    return (ushort)(r >> 16);
}

// ---------------------------------------------------------------------------
// prep: cnorm[k] = ||c_k||^2 (fp32) and bf16 codebook copy. One wave per code.
// ---------------------------------------------------------------------------
__global__ __launch_bounds__(256) void prep_kernel(const float* __restrict__ cb,
                                                   float* __restrict__ cnorm,
                                                   ushort* __restrict__ cbbf) {
    int code = (blockIdx.x * 256 + threadIdx.x) >> 6;
    int lane = threadIdx.x & 63;
    float4 v = ((const float4*)(cb + (size_t)code * D_))[lane];
    float s = v.x * v.x + v.y * v.y + v.z * v.z + v.w * v.w;
    #pragma unroll
    for (int off = 32; off; off >>= 1) s += __shfl_down(s, off);
    union { ushort us[4]; uint2 u2; } pk;
    pk.us[0] = f2bf(v.x); pk.us[1] = f2bf(v.y); pk.us[2] = f2bf(v.z); pk.us[3] = f2bf(v.w);
    ((uint2*)(cbbf + (size_t)code * D_))[lane] = pk.u2;
    if (lane == 0) cnorm[code] = s;
}

// ---------------------------------------------------------------------------
// gemm_top2 v2 (transposed): A = codebook chunk (32 codes), B = embeddings
// (position-stationary in registers). C[code][pos]: col=lane&31=position,
// rows=codes -> per-lane in-register top-2, no score LDS round-trip.
//   Block = 128 threads (2 waves) x 128 positions (64/wave, 2 pos-tiles).
//   Codebook streams through 2 x 16KB LDS buffers, 1 barrier/chunk,
//   stage(n+1) issued right after barrier, consumed next iteration.
//   Selection of chunk n-1 pipelined in registers under chunk n's MFMAs.
// ---------------------------------------------------------------------------
#define TOP2(SV, IV, B1, I1, B2, I2) {                                          \
    bool lt1 = (SV) < (B1); bool lt2 = (SV) < (B2);                             \
    B2 = lt1 ? B1 : (lt2 ? (SV) : B2);                                          \
    I2 = lt1 ? I1 : (lt2 ? (IV) : I2);                                          \
    B1 = lt1 ? (SV) : B1;                                                       \
    I1 = lt1 ? (IV) : I1; }

// stage 32 codes (16KB = 1024 x 16B units) of chunk CIDX into BUF.
// unit u of local code n stored at LDS unit n*32 + (u ^ (n&7))  (swizzle).
#define STAGE(CIDX, BUF) {                                                      \
    int wub = __builtin_amdgcn_readfirstlane((t >> 6) * 512);                   \
    _Pragma("unroll")                                                           \
    for (int i_ = 0; i_ < 8; ++i_) {                                            \
      int slot = wub + i_ * 64 + (t & 63);                                      \
      int n_ = slot >> 5, up_ = slot & 31;                                      \
      int u_ = up_ ^ (n_ & 7);                                                  \
      GL_LDS(cbbf + (((size_t)(CIDX) * 32 + n_) << 8) + (u_ << 3),              \
             (char*)(BUF) + (size_t)(wub + i_ * 64) * 16);                      \
    } }

// MFMA over one 32-code chunk into A0/A1 (zeroed first); if DO_SEL, run the
// top-2 selection of the PREVIOUS chunk (accs P0/P1, chunk index PNC) fused
// under the MFMAs.
#define PROCESS_BODY(BUF, A0, A1, DO_SEL, P0, P1, PNC) {                        \
    _Pragma("unroll")                                                           \
    for (int j_ = 0; j_ < 16; ++j_) { A0[j_] = 0.f; A1[j_] = 0.f; }             \
    float cna[16]; int ib0 = 0;                                                 \
    if (DO_SEL) {                                                               \
      const float* cp_ = cnorm + (PNC) * 32 + 4 * h;                            \
      *(float4*)&cna[0]  = *(const float4*)(cp_);                               \
      *(float4*)&cna[4]  = *(const float4*)(cp_ + 8);                           \
      *(float4*)&cna[8]  = *(const float4*)(cp_ + 16);                          \
      *(float4*)&cna[12] = *(const float4*)(cp_ + 24);                          \
      ib0 = (PNC) * 32 + 4 * h;                                                 \
    }                                                                           \
    _Pragma("unroll")                                                           \
    for (int s_ = 0; s_ < 16; ++s_) {                                           \
      bf16x8 aF = *(const bf16x8*)((const char*)(BUF) +                         \
                    (((l31 << 5) + ((2 * s_ + h) ^ swz)) << 4));                \
      A0 = __builtin_amdgcn_mfma_f32_32x32x16_bf16(aF, bfrag[0][s_], A0, 0,0,0);\
      A1 = __builtin_amdgcn_mfma_f32_32x32x16_bf16(aF, bfrag[1][s_], A1, 0,0,0);\
      if (DO_SEL) {                                                             \
        float sc0 = fmaf(-2.0f, P0[s_], cna[s_]);                               \
        float sc1 = fmaf(-2.0f, P1[s_], cna[s_]);                               \
        int idx_ = ib0 + (s_ & 3) + 8 * (s_ >> 2);                              \
        TOP2(sc0, idx_, b1[0], i1[0], b2[0], i2[0]);                            \
        TOP2(sc1, idx_, b1[1], i1[1], b2[1], i2[1]);                            \
      }                                                                         \
    } }

__global__ __launch_bounds__(128, 2) void gemm_top2_kernel(
    const int* __restrict__ ids, const int* __restrict__ masks,
    const float* __restrict__ table, const ushort* __restrict__ cbbf,
    const float* __restrict__ cnorm, int2* __restrict__ cand) {

  __shared__ ushort cbuf0[32 * 256];   // 16 KB
  __shared__ ushort cbuf1[32 * 256];   // 16 KB

  const int t    = threadIdx.x;
  const int lane = t & 63;
  const int l31  = lane & 31;
  const int h    = lane >> 5;
  const int w    = t >> 6;
  const int blk  = blockIdx.x;
  const int swz  = l31 & 7;

  // ---- B-frags: embeddings, position-stationary in registers ----
  // B[k][n]: n = lane&31 = position-in-tile, k = 16*s + 8*h + (0..7)
  bf16x8 bfrag[2][16];
  #pragma unroll
  for (int pt = 0; pt < 2; ++pt) {
    int pos = blk * 128 + w * 64 + pt * 32 + l31;
    int id  = ids[pos];
    float m = (masks[pos] >= 1) ? 1.0f : 0.0f;
    const float* er = table + (size_t)id * D_ + 8 * h;
    #pragma unroll
    for (int s = 0; s < 16; ++s) {
      float4 x = *(const float4*)(er + 16 * s);
      float4 y = *(const float4*)(er + 16 * s + 4);
      bf16x8 b;
      b[0] = (__bf16)(x.x * m); b[1] = (__bf16)(x.y * m);
      b[2] = (__bf16)(x.z * m); b[3] = (__bf16)(x.w * m);
      b[4] = (__bf16)(y.x * m); b[5] = (__bf16)(y.y * m);
      b[6] = (__bf16)(y.z * m); b[7] = (__bf16)(y.w * m);
      bfrag[pt][s] = b;
    }
  }

  float b1[2], b2[2]; int i1[2], i2[2];
  b1[0] = b1[1] = b2[0] = b2[1] = 3.0e38f;
  i1[0] = i1[1] = i2[0] = i2[1] = 0;

  f32x16 aE0, aE1, aO0, aO1;

  STAGE(0, cbuf0);
  __syncthreads();                 // drains chunk-0 stage
  STAGE(1, cbuf1);
  PROCESS_BODY(cbuf0, aE0, aE1, false, aE0, aE1, 0);   // chunk 0, no select

  #pragma unroll 1
  for (int nc = 1; nc < 63; nc += 2) {
    __syncthreads();               // cbuf0 readers done; drains stage(nc->cbuf1)
    STAGE(nc + 1, cbuf0);
    PROCESS_BODY(cbuf1, aO0, aO1, true, aE0, aE1, nc - 1);
    __syncthreads();               // cbuf1 readers done; drains stage(nc+1->cbuf0)
    STAGE(nc + 2, cbuf1);
    PROCESS_BODY(cbuf0, aE0, aE1, true, aO0, aO1, nc);
  }
  __syncthreads();                 // drains stage(63->cbuf1)
  PROCESS_BODY(cbuf1, aO0, aO1, true, aE0, aE1, 62);

  // ---- standalone select for chunk 63 ----
  {
    const float* cp = cnorm + 63 * 32 + 4 * h;
    float cna[16];
    *(float4*)&cna[0]  = *(const float4*)(cp);
    *(float4*)&cna[4]  = *(const float4*)(cp + 8);
    *(float4*)&cna[8]  = *(const float4*)(cp + 16);
    *(float4*)&cna[12] = *(const float4*)(cp + 24);
    int ib0 = 63 * 32 + 4 * h;
    #pragma unroll
    for (int j = 0; j < 16; ++j) {
      float s0 = fmaf(-2.0f, aO0[j], cna[j]);
      float s1 = fmaf(-2.0f, aO1[j], cna[j]);
      int idx = ib0 + (j & 3) + 8 * (j >> 2);
      TOP2(s0, idx, b1[0], i1[0], b2[0], i2[0]);
      TOP2(s1, idx, b1[1], i1[1], b2[1], i2[1]);
    }
  }

  // ---- merge h=0/h=1 partner lanes (same position, disjoint code rows) ----
  #pragma unroll
  for (int pt = 0; pt < 2; ++pt) {
    float ob1 = __shfl_xor(b1[pt], 32);
    float ob2 = __shfl_xor(b2[pt], 32);
    int   oi1 = __shfl_xor(i1[pt], 32);
    int   oi2 = __shfl_xor(i2[pt], 32);
    bool of = (ob1 < b1[pt]) || (ob1 == b1[pt] && oi1 < i1[pt]);
    float f1s = of ? ob1 : b1[pt]; int g1 = of ? oi1 : i1[pt];
    float ca  = of ? b1[pt] : ob1; int cia = of ? i1[pt] : oi1;
    float cb  = of ? ob2 : b2[pt]; int cib = of ? oi2 : i2[pt];
    bool bs = (cb < ca) || (cb == ca && cib < cia);
    int g2 = bs ? cib : cia;
    (void)f1s;
    if (h == 0) cand[blk * 128 + w * 64 + pt * 32 + l31] = make_int2(g1, g2);
  }
}

// ---------------------------------------------------------------------------
// rescore: exact fp32 distance for the 2 candidates; first-min tie-break.
// ---------------------------------------------------------------------------
__global__ __launch_bounds__(256) void rescore_kernel(
    const int* __restrict__ ids, const int* __restrict__ masks,
    const float* __restrict__ table, const float* __restrict__ cb,
    const float* __restrict__ cnorm, const int2* __restrict__ cand,
    int* __restrict__ idx_out) {

    int u = blockIdx.x * 4 + (threadIdx.x >> 6);
    int lane = threadIdx.x & 63;
    int2 c = cand[u];
    int lo = min(c.x, c.y), hi = max(c.x, c.y);
    int id = ids[u];
    float m = (masks[u] >= 1) ? 1.0f : 0.0f;
    float4 e = ((const float4*)(table + (size_t)id * D_))[lane];
    e.x *= m; e.y *= m; e.z *= m; e.w *= m;
    float4 a = ((const float4*)(cb + (size_t)lo * D_))[lane];
    float4 b = ((const float4*)(cb + (size_t)hi * D_))[lane];
    float s1 = fmaf(e.x, a.x, fmaf(e.y, a.y, fmaf(e.z, a.z, e.w * a.w)));
    float s2 = fmaf(e.x, b.x, fmaf(e.y, b.y, fmaf(e.z, b.z, e.w * b.w)));
    #pragma unroll
    for (int off = 32; off; off >>= 1) {
        s1 += __shfl_xor(s1, off);
        s2 += __shfl_xor(s2, off);
    }
    if (lane == 0) {
        float d1 = cnorm[lo] - 2.0f * s1;
        float d2 = cnorm[hi] - 2.0f * s2;
        idx_out[u] = (d2 < d1) ? hi : lo;   // tie -> lo (first minimum)
    }
}

// ---------------------------------------------------------------------------
// reduce_dense: per-batch masked means + concat + dense.
// ---------------------------------------------------------------------------
__global__ __launch_bounds__(256) void reduce_dense_kernel(
    const int* __restrict__ ids, const int* __restrict__ masks,
    const float* __restrict__ table, const float* __restrict__ cb,
    const int* __restrict__ vq_idx, const float* __restrict__ W,
    const float* __restrict__ bvec, float* __restrict__ out) {

    __shared__ float x[2 * D_];
    const int b = blockIdx.x;
    const int d = threadIdx.x;

    const int* idrow = ids    + b * L_;
    const int* mrow  = masks  + b * L_;
    const int* qrow  = vq_idx + b * L_;

    float esum = 0.f, vsum = 0.f;
    int count = 0;
    for (int l = 0; l < L_; ++l) {
        int id = idrow[l];
        int mv = mrow[l];
        int q  = qrow[l];
        float m = (mv >= 1) ? 1.0f : 0.0f;
        count += (mv >= 1) ? 1 : 0;
        esum = fmaf(m, table[(size_t)id * D_ + d], esum);
        vsum += cb[(size_t)q * D_ + d];
    }
    float fc = (float)count;
    x[d]      = vsum / fc;            // vq_mean: no eps
    x[D_ + d] = esum / (fc + 1e-9f);  // hist_mean: +1e-9
    __syncthreads();

    float acc = bvec[d];
    for (int i = 0; i < 2 * D_; ++i)
        acc = fmaf(x[i], W[i * D_ + d], acc);
    out[(size_t)b * D_ + d] = acc;
}

// ---------------------------------------------------------------------------
extern "C" void kernel_launch(void* const* d_in, const int* in_sizes, int n_in,
                              void* d_out, int out_size, void* d_ws, size_t ws_size,
                              hipStream_t stream) {
    const int*   ids   = (const int*)  d_in[0];
    const int*   masks = (const int*)  d_in[1];
    const float* table = (const float*)d_in[2];
    const float* cb    = (const float*)d_in[3];
    const float* W     = (const float*)d_in[4];
    const float* bvec  = (const float*)d_in[5];
    float* out = (float*)d_out;

    float*  cnorm = (float*)d_ws;                                   // 8 KB
    ushort* cbbf  = (ushort*)((char*)d_ws + 8192);                  // 1 MB
    int2*   cand  = (int2*)((char*)d_ws + 8192 + 1048576);          // 800 KB
    int*    idx   = (int*)((char*)cand + (size_t)BL_ * sizeof(int2));

    prep_kernel<<<K_ * 64 / 256, 256, 0, stream>>>(cb, cnorm, cbbf);
    gemm_top2_kernel<<<BL_ / 128, 128, 0, stream>>>(ids, masks, table, cbbf, cnorm, cand);
    rescore_kernel<<<BL_ / 4, 256, 0, stream>>>(ids, masks, table, cb, cnorm, cand, idx);
    reduce_dense_kernel<<<B_, 256, 0, stream>>>(ids, masks, table, cb, idx, W, bvec, out);
}

// Round 4
// 387.511 us; speedup vs baseline: 16.6111x; 1.0706x over previous
//
#include <hip/hip_runtime.h>
#include <hip/hip_bf16.h>
#include <cstddef>
#include <cstdint>

#define B_  512
#define L_  200
#define D_  256
#define K_  2048
#define BL_ (B_ * L_)

typedef __bf16 bf16x8 __attribute__((ext_vector_type(8)));
typedef float  f32x16 __attribute__((ext_vector_type(16)));

#define GL_LDS(g, l) __builtin_amdgcn_global_load_lds(                          \
    (const __attribute__((address_space(1))) void*)(g),                         \
    (__attribute__((address_space(3))) void*)(l), 16, 0, 0)

__device__ inline ushort f2bf(float f) {   // RNE float->bf16 (no NaN in data)
    union { float f; uint u; } a; a.f = f;
    uint r = a.u + 0x7FFFu + ((a.u >> 16) & 1u);
    return (ushort)(r >> 16);
}

// ---------------------------------------------------------------------------
// prep: cnorm[k] = ||c_k||^2 (fp32) and bf16 codebook copy. One wave per code.
// ---------------------------------------------------------------------------
__global__ __launch_bounds__(256) void prep_kernel(const float* __restrict__ cb,
                                                   float* __restrict__ cnorm,
                                                   ushort* __restrict__ cbbf) {
    int code = (blockIdx.x * 256 + threadIdx.x) >> 6;
    int lane = threadIdx.x & 63;
    float4 v = ((const float4*)(cb + (size_t)code * D_))[lane];
    float s = v.x * v.x + v.y * v.y + v.z * v.z + v.w * v.w;
    #pragma unroll
    for (int off = 32; off; off >>= 1) s += __shfl_down(s, off);
    union { ushort us[4]; uint2 u2; } pk;
    pk.us[0] = f2bf(v.x); pk.us[1] = f2bf(v.y); pk.us[2] = f2bf(v.z); pk.us[3] = f2bf(v.w);
    ((uint2*)(cbbf + (size_t)code * D_))[lane] = pk.u2;
    if (lane == 0) cnorm[code] = s;
}

// ---------------------------------------------------------------------------
// gemm_top2 v3: A = codebook chunk (32 codes, LDS dbuf), B = -2*embeddings
// (position-stationary in registers). Accumulator INITIALIZED with cnorm ->
// acc = cnorm - 2*e.c = score directly. Selection inline per chunk (single
// accumulator generation -> no spill). One barrier per chunk.
// ---------------------------------------------------------------------------
#define TOP2(SV, IV, B1, I1, B2, I2) {                                          \
    bool lt1 = (SV) < (B1); bool lt2 = (SV) < (B2);                             \
    B2 = lt1 ? B1 : (lt2 ? (SV) : B2);                                          \
    I2 = lt1 ? I1 : (lt2 ? (IV) : I2);                                          \
    B1 = lt1 ? (SV) : B1;                                                       \
    I1 = lt1 ? (IV) : I1; }

// stage 32 codes (16KB = 1024 x 16B units) of chunk CIDX into BUF.
// unit u of local code n stored at LDS unit n*32 + (u ^ (n&7))  (swizzle).
#define STAGE(CIDX, BUF) {                                                      \
    int wub = __builtin_amdgcn_readfirstlane((t >> 6) * 512);                   \
    _Pragma("unroll")                                                           \
    for (int i_ = 0; i_ < 8; ++i_) {                                            \
      int slot = wub + i_ * 64 + (t & 63);                                      \
      int n_ = slot >> 5, up_ = slot & 31;                                      \
      int u_ = up_ ^ (n_ & 7);                                                  \
      GL_LDS(cbbf + (((size_t)(CIDX) * 32 + n_) << 8) + (u_ << 3),              \
             (char*)(BUF) + (size_t)(wub + i_ * 64) * 16);                      \
    } }

// Process one 32-code chunk: acc init = cnorm, 16 MFMA steps, inline top-2.
#define PROCSEL(BUF, NC) {                                                      \
    f32x16 A0, A1;                                                              \
    {                                                                           \
      const float* cp_ = cnorm + (NC) * 32 + 4 * h;                             \
      float4 c0_ = *(const float4*)(cp_);                                       \
      float4 c1_ = *(const float4*)(cp_ + 8);                                   \
      float4 c2_ = *(const float4*)(cp_ + 16);                                  \
      float4 c3_ = *(const float4*)(cp_ + 24);                                  \
      A0[0]=c0_.x; A0[1]=c0_.y; A0[2]=c0_.z; A0[3]=c0_.w;                       \
      A0[4]=c1_.x; A0[5]=c1_.y; A0[6]=c1_.z; A0[7]=c1_.w;                       \
      A0[8]=c2_.x; A0[9]=c2_.y; A0[10]=c2_.z; A0[11]=c2_.w;                     \
      A0[12]=c3_.x; A0[13]=c3_.y; A0[14]=c3_.z; A0[15]=c3_.w;                   \
      A1 = A0;                                                                  \
    }                                                                           \
    _Pragma("unroll")                                                           \
    for (int s_ = 0; s_ < 16; ++s_) {                                           \
      bf16x8 aF = *(const bf16x8*)((const char*)(BUF) +                         \
                    (((l31 << 5) + ((2 * s_ + h) ^ swz)) << 4));                \
      A0 = __builtin_amdgcn_mfma_f32_32x32x16_bf16(aF, bfrag[0][s_], A0, 0,0,0);\
      A1 = __builtin_amdgcn_mfma_f32_32x32x16_bf16(aF, bfrag[1][s_], A1, 0,0,0);\
    }                                                                           \
    int ib0_ = (NC) * 32 + 4 * h;                                               \
    _Pragma("unroll")                                                           \
    for (int j_ = 0; j_ < 16; ++j_) {                                           \
      int idx_ = ib0_ + (j_ & 3) + 8 * (j_ >> 2);                               \
      float s0_ = A0[j_], s1_ = A1[j_];                                         \
      TOP2(s0_, idx_, b1[0], i1[0], b2[0], i2[0]);                              \
      TOP2(s1_, idx_, b1[1], i1[1], b2[1], i2[1]);                              \
    } }

__global__ __launch_bounds__(128, 2) void gemm_top2_kernel(
    const int* __restrict__ ids, const int* __restrict__ masks,
    const float* __restrict__ table, const ushort* __restrict__ cbbf,
    const float* __restrict__ cnorm, int2* __restrict__ cand) {

  __shared__ ushort cbuf0[32 * 256];   // 16 KB
  __shared__ ushort cbuf1[32 * 256];   // 16 KB

  const int t    = threadIdx.x;
  const int lane = t & 63;
  const int l31  = lane & 31;
  const int h    = lane >> 5;
  const int w    = t >> 6;
  const int blk  = blockIdx.x;
  const int swz  = l31 & 7;

  // ---- B-frags: -2 * embeddings, position-stationary in registers ----
  // B[k][n]: n = lane&31 = position-in-tile, k = 16*s + 8*h + (0..7)
  bf16x8 bfrag[2][16];
  #pragma unroll
  for (int pt = 0; pt < 2; ++pt) {
    int pos = blk * 128 + w * 64 + pt * 32 + l31;
    int id  = ids[pos];
    float m = (masks[pos] >= 1) ? -2.0f : 0.0f;   // fold -2 scale + mask
    const float* er = table + (size_t)id * D_ + 8 * h;
    #pragma unroll
    for (int s = 0; s < 16; ++s) {
      float4 x = *(const float4*)(er + 16 * s);
      float4 y = *(const float4*)(er + 16 * s + 4);
      bf16x8 b;
      b[0] = (__bf16)(x.x * m); b[1] = (__bf16)(x.y * m);
      b[2] = (__bf16)(x.z * m); b[3] = (__bf16)(x.w * m);
      b[4] = (__bf16)(y.x * m); b[5] = (__bf16)(y.y * m);
      b[6] = (__bf16)(y.z * m); b[7] = (__bf16)(y.w * m);
      bfrag[pt][s] = b;
    }
  }

  float b1[2], b2[2]; int i1[2], i2[2];
  b1[0] = b1[1] = b2[0] = b2[1] = 3.0e38f;
  i1[0] = i1[1] = i2[0] = i2[1] = 0;

  STAGE(0, cbuf0);
  __syncthreads();                 // drains chunk-0 stage

  #pragma unroll 1
  for (int nc = 0; nc < 64; nc += 2) {
    STAGE(nc + 1, cbuf1);          // nc <= 62 so nc+1 <= 63 always valid
    PROCSEL(cbuf0, nc);
    __syncthreads();               // cbuf0 readers done; drains stage->cbuf1
    if (nc + 2 < 64) STAGE(nc + 2, cbuf0);
    PROCSEL(cbuf1, nc + 1);
    __syncthreads();               // cbuf1 readers done; drains stage->cbuf0
  }

  // ---- merge h=0/h=1 partner lanes (same position, disjoint code rows) ----
  #pragma unroll
  for (int pt = 0; pt < 2; ++pt) {
    float ob1 = __shfl_xor(b1[pt], 32);
    float ob2 = __shfl_xor(b2[pt], 32);
    int   oi1 = __shfl_xor(i1[pt], 32);
    int   oi2 = __shfl_xor(i2[pt], 32);
    bool of = (ob1 < b1[pt]) || (ob1 == b1[pt] && oi1 < i1[pt]);
    int g1 = of ? oi1 : i1[pt];
    float ca  = of ? b1[pt] : ob1; int cia = of ? i1[pt] : oi1;
    float cb  = of ? ob2 : b2[pt]; int cib = of ? oi2 : i2[pt];
    bool bs = (cb < ca) || (cb == ca && cib < cia);
    int g2 = bs ? cib : cia;
    if (h == 0) cand[blk * 128 + w * 64 + pt * 32 + l31] = make_int2(g1, g2);
  }
}

// ---------------------------------------------------------------------------
// reduce_dense (rescore fused):
//  phase 1: wave-per-position exact fp32 rescore of the 2 candidates
//  phase 2: thread-per-dim masked means + concat + dense (rows L2-warm).
// ---------------------------------------------------------------------------
__global__ __launch_bounds__(256) void reduce_dense_kernel(
    const int* __restrict__ ids, const int* __restrict__ masks,
    const float* __restrict__ table, const float* __restrict__ cb,
    const float* __restrict__ cnorm, const int2* __restrict__ cand,
    const float* __restrict__ W, const float* __restrict__ bvec,
    float* __restrict__ out) {

    __shared__ float x[2 * D_];
    __shared__ int qidx[L_];
    const int b = blockIdx.x;
    const int t = threadIdx.x;
    const int wv = t >> 6, lane = t & 63;

    // ---- phase 1: rescore ----
    for (int l = wv; l < L_; l += 4) {
        int u = b * L_ + l;
        int2 c = cand[u];
        int lo = min(c.x, c.y), hi = max(c.x, c.y);
        int id = ids[u];
        float m = (masks[u] >= 1) ? 1.0f : 0.0f;
        float4 e = ((const float4*)(table + (size_t)id * D_))[lane];
        e.x *= m; e.y *= m; e.z *= m; e.w *= m;
        float4 a = ((const float4*)(cb + (size_t)lo * D_))[lane];
        float4 bb = ((const float4*)(cb + (size_t)hi * D_))[lane];
        float s1 = fmaf(e.x, a.x, fmaf(e.y, a.y, fmaf(e.z, a.z, e.w * a.w)));
        float s2 = fmaf(e.x, bb.x, fmaf(e.y, bb.y, fmaf(e.z, bb.z, e.w * bb.w)));
        #pragma unroll
        for (int off = 32; off; off >>= 1) {
            s1 += __shfl_xor(s1, off);
            s2 += __shfl_xor(s2, off);
        }
        if (lane == 0) {
            float d1 = cnorm[lo] - 2.0f * s1;
            float d2 = cnorm[hi] - 2.0f * s2;
            qidx[l] = (d2 < d1) ? hi : lo;   // tie -> lo (first minimum)
        }
    }
    __syncthreads();

    // ---- phase 2: means + dense ----
    const int d = t;   // 256 threads == D_
    const int* idrow = ids   + b * L_;
    const int* mrow  = masks + b * L_;

    float esum = 0.f, vsum = 0.f;
    int count = 0;
    for (int l = 0; l < L_; ++l) {
        int id = idrow[l];
        int mv = mrow[l];
        int q  = qidx[l];
        float m = (mv >= 1) ? 1.0f : 0.0f;
        count += (mv >= 1) ? 1 : 0;
        esum = fmaf(m, table[(size_t)id * D_ + d], esum);
        vsum += cb[(size_t)q * D_ + d];       // includes masked positions (ref)
    }
    float fc = (float)count;
    x[d]      = vsum / fc;            // vq_mean: no eps
    x[D_ + d] = esum / (fc + 1e-9f);  // hist_mean: +1e-9
    __syncthreads();

    float acc = bvec[d];
    for (int i = 0; i < 2 * D_; ++i)
        acc = fmaf(x[i], W[i * D_ + d], acc);
    out[(size_t)b * D_ + d] = acc;
}

// ---------------------------------------------------------------------------
extern "C" void kernel_launch(void* const* d_in, const int* in_sizes, int n_in,
                              void* d_out, int out_size, void* d_ws, size_t ws_size,
                              hipStream_t stream) {
    const int*   ids   = (const int*)  d_in[0];
    const int*   masks = (const int*)  d_in[1];
    const float* table = (const float*)d_in[2];
    const float* cb    = (const float*)d_in[3];
    const float* W     = (const float*)d_in[4];
    const float* bvec  = (const float*)d_in[5];
    float* out = (float*)d_out;

    float*  cnorm = (float*)d_ws;                                   // 8 KB
    ushort* cbbf  = (ushort*)((char*)d_ws + 8192);                  // 1 MB
    int2*   cand  = (int2*)((char*)d_ws + 8192 + 1048576);          // 800 KB

    prep_kernel<<<K_ * 64 / 256, 256, 0, stream>>>(cb, cnorm, cbbf);
    gemm_top2_kernel<<<BL_ / 128, 128, 0, stream>>>(ids, masks, table, cbbf, cnorm, cand);
    reduce_dense_kernel<<<B_, 256, 0, stream>>>(ids, masks, table, cb, cnorm, cand, W, bvec, out);
}